// Round 1
// baseline (685.477 us; speedup 1.0000x reference)
//
#include <hip/hip_runtime.h>

#define NN        10000   // nodes
#define D_IN      256     // in channels
#define EE        8192    // target edges
#define GROUPS    157     // u64 words per packed row (ceil(10000/64))
#define ROW_U64   160     // padded packed-row stride in u64
#define UNITS     1250    // 8-byte units per row (10000/8), one mask byte each
#define UNITS16   625     // 16-byte units per row (10000/16), one mask ushort each

typedef unsigned long long u64;

// Encoding probe: adj01 byte offset 10001.
//   byte encoding  -> adj01[1,1] diagonal, guaranteed 1 (adj01 |= eye)
//   int32 encoding -> byte 1 of element 2500 (value 0 or 1), guaranteed 0
__device__ __forceinline__ bool probe_is_byte(const unsigned char* adj01_bytes) {
    return adj01_bytes[10001] != 0;
}

// ---------------------------------------------------------------------------
// Fused per-node kernel (one block per node n):
//   y1[n] = x[n,:]·W[D:2D]   (cn0 weight)
//   y2[n] = x[n,:]·W[2D:3D]  (cn1 weight)
//   p1[n,:] = bit-packed adj1 row n
// ---------------------------------------------------------------------------
__global__ void node_kernel(const float* __restrict__ x,
                            const float* __restrict__ W,
                            const void* __restrict__ adj1,
                            const unsigned char* __restrict__ adj01_bytes,
                            float* __restrict__ y1,
                            float* __restrict__ y2,
                            u64* __restrict__ p1) {
    const int n = blockIdx.x, tid = threadIdx.x;

    // ---- y1/y2 dot products ----
    const float p = x[(size_t)n * D_IN + tid];
    float s1 = p * W[D_IN + tid];
    float s2 = p * W[2 * D_IN + tid];
    #pragma unroll
    for (int off = 32; off > 0; off >>= 1) {
        s1 += __shfl_down(s1, off);
        s2 += __shfl_down(s2, off);
    }
    __shared__ float q1[4], q2[4];
    const int lane = tid & 63, wid = tid >> 6;
    if (lane == 0) { q1[wid] = s1; q2[wid] = s2; }

    // ---- bit-pack adj1 row n ----
    unsigned char* drow = (unsigned char*)(p1 + (size_t)n * ROW_U64);
    if (probe_is_byte(adj01_bytes)) {
        // 16 bytes (= 16 columns) per lane per iteration; one ushort store.
        const ulonglong2* src =
            (const ulonglong2*)((const unsigned char*)adj1 + (size_t)n * NN);
        unsigned short* drow16 = (unsigned short*)drow;
        #pragma unroll 3
        for (int u = tid; u < UNITS16; u += 256) {
            const ulonglong2 v = src[u];
            unsigned m = 0;
            #pragma unroll
            for (int b = 0; b < 8; ++b)
                m |= ((v.x >> (8 * b)) & 0xFFull) ? (1u << b) : 0u;
            #pragma unroll
            for (int b = 0; b < 8; ++b)
                m |= ((v.y >> (8 * b)) & 0xFFull) ? (1u << (8 + b)) : 0u;
            drow16[u] = (unsigned short)m;
        }
    } else {
        const uint4* src = (const uint4*)((const int*)adj1 + (size_t)n * NN);
        #pragma unroll 5
        for (int u = tid; u < UNITS; u += 256) {
            const uint4 a = src[2 * u], b = src[2 * u + 1];
            const unsigned m = (a.x ? 1u : 0u) | (a.y ? 2u : 0u) | (a.z ? 4u : 0u) |
                               (a.w ? 8u : 0u) | (b.x ? 16u : 0u) | (b.y ? 32u : 0u) |
                               (b.z ? 64u : 0u) | (b.w ? 128u : 0u);
            drow[u] = (unsigned char)m;
        }
    }
    for (int b = UNITS + tid; b < ROW_U64 * 8; b += 256) drow[b] = 0;  // pad

    __syncthreads();
    if (tid == 0) {
        y1[n] = q1[0] + q1[1] + q1[2] + q1[3];
        y2[n] = q2[0] + q2[1] + q2[2] + q2[3];
    }
}

// ---------------------------------------------------------------------------
// Per-edge (one block per edge e):
//   out[e] = sum_d x[ti,d]x[tj,d]W[d] + sum_{cn1} y2 + closed-form cn0 + b
//   cn1 = adj1[ti,:] & adj1[tj,:]  (packed-row AND)
//   cn0 (ti!=tj): tj iff a[ti,tj]&&!a[tj,tj];  ti iff a[tj,ti]&&!a[ti,ti]
//   cn0 (ti==tj): ti iff !a[ti,ti]
// ---------------------------------------------------------------------------
__global__ void edge_packed_kernel(const float* __restrict__ x,
                                   const int* __restrict__ tar,
                                   const float* __restrict__ W,
                                   const float* __restrict__ bxs,
                                   const float* __restrict__ y1,
                                   const float* __restrict__ y2,
                                   const u64* __restrict__ p1,
                                   float* __restrict__ out) {
    const int e = blockIdx.x, tid = threadIdx.x;
    const int ti = tar[e], tj = tar[EE + e];
    const u64* __restrict__ ri = p1 + (size_t)ti * ROW_U64;
    const u64* __restrict__ rj = p1 + (size_t)tj * ROW_U64;

    float acc = x[(size_t)ti * D_IN + tid] * x[(size_t)tj * D_IN + tid] * W[tid];

    if (tid < GROUPS) {
        u64 c1 = ri[tid] & rj[tid];
        const int base = tid * 64;
        while (c1) { acc += y2[base + __builtin_ctzll(c1)]; c1 &= c1 - 1; }
    }

    if (tid == 0) {
        #define BIT(row, c) ((int)(((row)[(c) >> 6] >> ((c) & 63)) & 1ull))
        if (ti != tj) {
            if (BIT(ri, tj) && !BIT(rj, tj)) acc += y1[tj];
            if (BIT(rj, ti) && !BIT(ri, ti)) acc += y1[ti];
        } else {
            if (!BIT(ri, ti)) acc += y1[ti];
        }
        #undef BIT
    }

    #pragma unroll
    for (int off = 32; off > 0; off >>= 1) acc += __shfl_down(acc, off);
    __shared__ float part[4];
    const int lane = tid & 63, wid = tid >> 6;
    if (lane == 0) part[wid] = acc;
    __syncthreads();
    if (tid == 0) out[e] = part[0] + part[1] + part[2] + part[3] + bxs[0];
}

// ---------------------------------------------------------------------------
// Fallback (ws too small for bitmap): direct adj1 row scan, same math.
// ---------------------------------------------------------------------------
__global__ void edge_direct_kernel(const float* __restrict__ x,
                                   const void* __restrict__ adj1,
                                   const unsigned char* __restrict__ adj01_bytes,
                                   const int* __restrict__ tar,
                                   const float* __restrict__ W,
                                   const float* __restrict__ bxs,
                                   const float* __restrict__ y1,
                                   const float* __restrict__ y2,
                                   float* __restrict__ out) {
    const int e = blockIdx.x, tid = threadIdx.x;
    const int ti = tar[e], tj = tar[EE + e];
    const bool isByte = probe_is_byte(adj01_bytes);
    float acc = x[(size_t)ti * D_IN + tid] * x[(size_t)tj * D_IN + tid] * W[tid];

    #define AD(r, c) (isByte ? (((const unsigned char*)adj1)[(size_t)(r) * NN + (c)] != 0) \
                             : (((const int*)adj1)[(size_t)(r) * NN + (c)] != 0))
    for (int n = tid; n < NN; n += 256)
        if (AD(ti, n) && AD(tj, n)) acc += y2[n];
    if (tid == 0) {
        if (ti != tj) {
            if (AD(ti, tj) && !AD(tj, tj)) acc += y1[tj];
            if (AD(tj, ti) && !AD(ti, ti)) acc += y1[ti];
        } else if (!AD(ti, ti)) acc += y1[ti];
    }
    #undef AD

    #pragma unroll
    for (int off = 32; off > 0; off >>= 1) acc += __shfl_down(acc, off);
    __shared__ float part[4];
    const int lane = tid & 63, wid = tid >> 6;
    if (lane == 0) part[wid] = acc;
    __syncthreads();
    if (tid == 0) out[e] = part[0] + part[1] + part[2] + part[3] + bxs[0];
}

// ---------------------------------------------------------------------------
extern "C" void kernel_launch(void* const* d_in, const int* in_sizes, int n_in,
                              void* d_out, int out_size, void* d_ws, size_t ws_size,
                              hipStream_t stream) {
    const float*         x     = (const float*)d_in[0];
    const unsigned char* adj01 = (const unsigned char*)d_in[1];  // probe only
    const void*          adj1  = d_in[2];
    const int*           tar   = (const int*)d_in[3];
    const float*         W     = (const float*)d_in[4];
    const float*         bxs   = (const float*)d_in[5];

    // ws layout: [y1:40000B][y2:40000B][pad][p1:12.8MB]
    float* y1 = (float*)d_ws;
    float* y2 = y1 + NN;
    u64*   p1 = (u64*)((char*)d_ws + ((2 * NN * sizeof(float) + 255) & ~255ull));
    const size_t need = ((2 * NN * sizeof(float) + 255) & ~255ull)
                      + (size_t)NN * ROW_U64 * sizeof(u64);

    float* out = (float*)d_out;

    if (ws_size >= need) {
        node_kernel<<<NN, 256, 0, stream>>>(x, W, adj1, adj01, y1, y2, p1);
        edge_packed_kernel<<<EE, 256, 0, stream>>>(x, tar, W, bxs, y1, y2, p1, out);
    } else {
        // still need y1/y2 (80 KB) — any sane ws has room
        node_kernel<<<NN, 256, 0, stream>>>(x, W, adj1, adj01, y1, y2, (u64*)y1 /*unused*/);
        edge_direct_kernel<<<EE, 256, 0, stream>>>(x, adj1, adj01, tar, W, bxs, y1, y2, out);
    }
}